// Round 3
// baseline (186.234 us; speedup 1.0000x reference)
//
#include <hip/hip_runtime.h>
#include <hip/hip_bf16.h>

#define BATCH 32
#define LSEQ  512
#define NDIM  1024
#define NSPLIT 16

typedef __attribute__((ext_vector_type(8))) short bf16x8;
typedef __attribute__((ext_vector_type(4))) float f32x4;

__device__ __forceinline__ unsigned short f2bf(float x) {
    __hip_bfloat16 h = __float2bfloat16(x);
    return __builtin_bit_cast(unsigned short, h);
}

// ---------------------------------------------------------------------------
// Kernel 1: fused X fp32 -> bf16 conversion + s1/s2 partial sums.
// R3: n-axis split x2 (grid z) -> 1024 blocks = 16 waves/CU (was 8) for MLP.
// Same per-(sp,b,n) FMA chain as before (bit-identical partials).
// ---------------------------------------------------------------------------
__global__ __launch_bounds__(256) void prep_kernel(
    const float* __restrict__ X, const float* __restrict__ W,
    unsigned short* __restrict__ Xb, float* __restrict__ P1, float* __restrict__ P2)
{
    __shared__ float sw[2 * LSEQ];
    int tid = threadIdx.x;
    for (int i = tid; i < 2 * LSEQ; i += 256) sw[i] = W[i];
    __syncthreads();

    int b  = blockIdx.y;
    int sp = blockIdx.x;
    int z  = blockIdx.z;
    int l0 = sp * (LSEQ / NSPLIT);
    int n  = z * 512 + tid * 2;
    size_t base = ((size_t)b * LSEQ + l0) * NDIM + n;
    const float* xp = X + base;
    unsigned short* xbp = Xb + base;

    float a0 = 0, a1 = 0, c0 = 0, c1 = 0;
    #pragma unroll 4
    for (int l = 0; l < LSEQ / NSPLIT; ++l) {
        float2 x = *(const float2*)(xp + (size_t)l * NDIM);
        float w1 = sw[l0 + l], w2 = sw[LSEQ + l0 + l];
        a0 = fmaf(x.x, w1, a0); a1 = fmaf(x.y, w1, a1);
        c0 = fmaf(x.x, w2, c0); c1 = fmaf(x.y, w2, c1);
        ushort2 u; u.x = f2bf(x.x); u.y = f2bf(x.y);
        *(ushort2*)(xbp + (size_t)l * NDIM) = u;
    }
    size_t po = ((size_t)sp * BATCH + b) * NDIM + n;
    *(float2*)(P1 + po) = make_float2(a0, a1);
    *(float2*)(P2 + po) = make_float2(c0, c1);
}

// ---------------------------------------------------------------------------
// Kernel 2: fused reduce + softmax-denominator stats (unchanged)
// ---------------------------------------------------------------------------
__global__ __launch_bounds__(256) void stats_kernel(
    const float* __restrict__ P1, const float* __restrict__ P2,
    float* __restrict__ s1, float* __restrict__ s2, float* __restrict__ rd)
{
    __shared__ float s1s[NDIM];
    __shared__ float s2s[128];
    int t = threadIdx.x;
    int b = blockIdx.x >> 3, sl = blockIdx.x & 7;
    int j0 = sl * 128;

    #pragma unroll
    for (int q = 0; q < 4; ++q) {
        int n = q * 256 + t;
        float a = 0.f;
        #pragma unroll
        for (int sp = 0; sp < NSPLIT; ++sp)
            a += P1[((size_t)sp * BATCH + b) * NDIM + n];
        s1s[n] = a;
        if (sl == 0) s1[b * NDIM + n] = a;
    }
    if (t < 128) {
        int j = j0 + t;
        float c = 0.f;
        #pragma unroll
        for (int sp = 0; sp < NSPLIT; ++sp)
            c += P2[((size_t)sp * BATCH + b) * NDIM + j];
        s2s[t] = c;
        s2[b * NDIM + j] = c;
    }
    __syncthreads();

    int jl = t >> 1, half = t & 1;
    int jg = j0 + jl;
    float s2j = s2s[jl];
    float sum = 0.f;
    int i0 = half * 512;
    for (int i = i0; i < i0 + 512; ++i) {
        float v = s1s[i] + s2j;
        v = fmaxf(v, 0.01f * v);          // leaky relu
        if (i == jg) v = 0.f;             // diag of e zeroed before softmax
        sum += __expf(v);
    }
    sum += __shfl_xor(sum, 1);
    if (half == 0) rd[b * NDIM + jg] = 1.0f / sum;
}

// ---------------------------------------------------------------------------
// Kernel 3: Bt[b][i][j] = exp(e_ij) * rd[b,j] in bf16 (unchanged)
// ---------------------------------------------------------------------------
__global__ __launch_bounds__(256) void btgen_kernel(
    const float* __restrict__ s1, const float* __restrict__ s2,
    const float* __restrict__ rd, unsigned short* __restrict__ Bt)
{
    int wid = threadIdx.x >> 6, lane = threadIdx.x & 63;
    int r = blockIdx.x * 4 + wid;          // (b,i) flat
    int b = r >> 10, i = r & 1023;
    float s1i = s1[r];
    const float* s2b = s2 + b * NDIM;
    const float* rdb = rd + b * NDIM;
    unsigned short* outp = Bt + (size_t)r * NDIM;

    #pragma unroll
    for (int q = 0; q < 2; ++q) {
        int j0 = q * 512 + lane * 8;
        float sv[8], rv[8];
        #pragma unroll
        for (int h = 0; h < 2; ++h) {
            float4 s4 = *(const float4*)(s2b + j0 + h * 4);
            float4 r4 = *(const float4*)(rdb + j0 + h * 4);
            sv[h*4+0]=s4.x; sv[h*4+1]=s4.y; sv[h*4+2]=s4.z; sv[h*4+3]=s4.w;
            rv[h*4+0]=r4.x; rv[h*4+1]=r4.y; rv[h*4+2]=r4.z; rv[h*4+3]=r4.w;
        }
        bf16x8 v;
        #pragma unroll
        for (int k = 0; k < 8; ++k) {
            float e = s1i + sv[k];
            e = fmaxf(e, 0.01f * e);       // leaky relu
            if (j0 + k == i) e = 0.f;      // diag of e zeroed (alpha nonzero there)
            v[k] = (short)f2bf(__expf(e) * rv[k]);
        }
        *(bf16x8*)&outp[j0] = v;
    }
}

// ---------------------------------------------------------------------------
// Kernel 4: batched GEMM  out[b] = sigmoid( Xb[b] (512x1024) @ Bt[b]^T )
//
// ROUND 3: faithful m201-style 8-phase schedule (4 phases per BK=64 tile,
// 2 tiles per dbuf pair). 256x256 tile, 8 waves (2Mx4N), per-wave 128x64.
//
// LDS: 2 dbufs x { A:[2kh][256rows][64B], B:[2kh][256][64B] } = 128 KiB.
//   A "region" = (op, kh) = 16 KB, staged by ONE 2-load step per thread.
//   Swizzle (64B rows): phys_chunk = log_chunk ^ ((row>>1)&3); applied to
//   the pre-swizzled GLOBAL source (linear LDS dest, rule #21) and to the
//   ds_read addresses. 16-lane fragment read spreads 2 per bank-group (free).
//
// Per tile t (dbuf D=t&1), 4 phases; each phase:
//   {issue ds_reads for this phase's 16 MFMAs; issue 1 region stage;
//    BARRIER; lgkmcnt(0); setprio(1); 16 MFMA; setprio(0); BARRIER}
//   phase0: A-kh0(x8)+B-kh0-ni01 reads; stage B-kh1(t+1) -> dbuf D^1
//   phase1: B-kh0-ni23 reads (A held in regs); stage A-kh0(t+2) -> D (A-kh0
//           last read in phase0, closed by phase0's lgkm0+barrier => WAR-safe)
//   phase2: A-kh1(x8)+B-kh1-ni01; stage B-kh0(t+2) -> D (closed @ phase1)
//   phase3: B-kh1-ni23; stage A-kh1(t+2) -> D (closed @ phase2)
// Tile entry: vmcnt(6) [= 3 regions in flight, template's N] + barrier
// (the barrier makes ALL waves' stages of tile t visible before any read).
// Prologue stages 7 regions; epilogue peels t=14 (phase0-stage only) and
// t=15 (no stage, vmcnt(0)).
// ---------------------------------------------------------------------------
#define WAITVM(n) asm volatile("s_waitcnt vmcnt(" #n ")" ::: "memory")
#define LGKM0()   asm volatile("s_waitcnt lgkmcnt(0)" ::: "memory")
#define BARF()    do { asm volatile("" ::: "memory");                          \
                       __builtin_amdgcn_s_barrier();                           \
                       asm volatile("" ::: "memory"); } while (0)

#define STAGE(PTR, OPB, KH, TT, DB) do {                                       \
    const char* s_ = (PTR) + (TT) * 128 + (KH) * 64;                           \
    __builtin_amdgcn_global_load_lds(                                          \
        (const __attribute__((address_space(1))) void*)s_,                     \
        (__attribute__((address_space(3))) void*)(LdsC + (DB) * 65536 + (OPB)  \
            + (KH) * 16384 + tid * 16), 16, 0, 0);                             \
    __builtin_amdgcn_global_load_lds(                                          \
        (const __attribute__((address_space(1))) void*)(s_ + 262144),          \
        (__attribute__((address_space(3))) void*)(LdsC + (DB) * 65536 + (OPB)  \
            + (KH) * 16384 + 8192 + tid * 16), 16, 0, 0);                      \
} while (0)

#define RDA(DB, KH, MI) (*(const bf16x8*)(LdsC + (DB) * 65536 +                \
                          (KH) * 16384 + abase + (MI) * 1024))
#define RDB(DB, KH, NI) (*(const bf16x8*)(LdsC + (DB) * 65536 + 32768 +        \
                          (KH) * 16384 + bbase + (NI) * 1024))

#define MFMA16(NH)                                                             \
    __builtin_amdgcn_s_setprio(1);                                             \
    _Pragma("unroll")                                                          \
    for (int ni2 = 0; ni2 < 2; ++ni2)                                          \
        _Pragma("unroll")                                                      \
        for (int mi = 0; mi < 8; ++mi)                                         \
            acc[mi][(NH) * 2 + ni2] = __builtin_amdgcn_mfma_f32_16x16x32_bf16( \
                av[mi], bv[ni2], acc[mi][(NH) * 2 + ni2], 0, 0, 0);            \
    __builtin_amdgcn_s_setprio(0);

#define TILE(TT, DB, SM) {                                                     \
    bf16x8 av[8], bv[2];                                                       \
    _Pragma("unroll")                                                          \
    for (int mi = 0; mi < 8; ++mi) av[mi] = RDA(DB, 0, mi);                    \
    bv[0] = RDB(DB, 0, 0); bv[1] = RDB(DB, 0, 1);                              \
    if ((SM) >= 1) STAGE(pB, 32768, 1, (TT) + 1, (DB) ^ 1);                    \
    BARF(); LGKM0(); MFMA16(0); BARF();                                        \
    bv[0] = RDB(DB, 0, 2); bv[1] = RDB(DB, 0, 3);                              \
    if ((SM) >= 2) STAGE(pA, 0, 0, (TT) + 2, DB);                              \
    BARF(); LGKM0(); MFMA16(1); BARF();                                        \
    _Pragma("unroll")                                                          \
    for (int mi = 0; mi < 8; ++mi) av[mi] = RDA(DB, 1, mi);                    \
    bv[0] = RDB(DB, 1, 0); bv[1] = RDB(DB, 1, 1);                              \
    if ((SM) >= 2) STAGE(pB, 32768, 0, (TT) + 2, DB);                          \
    BARF(); LGKM0(); MFMA16(0); BARF();                                        \
    bv[0] = RDB(DB, 1, 2); bv[1] = RDB(DB, 1, 3);                              \
    if ((SM) >= 2) STAGE(pA, 0, 1, (TT) + 2, DB);                              \
    BARF(); LGKM0(); MFMA16(1);                                                \
}

__global__ __launch_bounds__(512, 2) void gemm_kernel(
    const unsigned short* __restrict__ Xb, const unsigned short* __restrict__ Bt,
    float* __restrict__ out)
{
    // 2 dbufs x 64 KiB = 128 KiB
    __shared__ __align__(16) unsigned short LDSU[65536];
    char* LdsC = (char*)LDSU;

    const int tid = threadIdx.x, lane = tid & 63;
    const int wid = tid >> 6;
    const int wm = wid >> 2, wn = wid & 3;      // 2 x 4 wave grid

    // block mapping: 8 blocks/batch all on one XCD (flat&7 == b&7),
    // 4 batches per XCD, grid 256 = exactly 1 block/CU.
    int flat  = blockIdx.x;
    int xcd   = flat & 7;
    int p     = flat >> 3;
    int b     = (p >> 3) * 8 + xcd;
    int inner = p & 7;
    int mt = inner & 1, nt = inner >> 1;
    int l0 = mt * 256, n0 = nt * 256;

    const char* XgB = (const char*)(Xb + ((size_t)b * LSEQ + l0) * NDIM);
    const char* BgB = (const char*)(Bt + ((size_t)b * NDIM + n0) * NDIM);

    // Stage source pointers (pre-swizzled). Region chunk c = tid (+512):
    // row = c>>2 (0..127, +128 for second), slot = c&3.
    // logical 16B-chunk s at physical chunk s ^ ((row>>1)&3)  [involution].
    // row and row+128 share the same swizzle ((row>>1)&3 unchanged mod 4).
    {
    }
    const int srow  = tid >> 2;
    const int sswz  = ((srow >> 1) & 3) << 4;
    const int sloff = ((tid & 3) * 16) ^ sswz;
    const char* pA = XgB + (size_t)srow * 2048 + sloff;
    const char* pB = BgB + (size_t)srow * 2048 + sloff;

    // Fragment read bases. Fragment rows: wm*128 + mi*16 + rsel (A),
    // wn*64 + ni*16 + rsel (B); (row>>1)&3 == (rsel>>1)&3 for all mi/ni/wm/wn
    // (those add multiples of 8 after >>1), so swizzle is per-lane constant.
    const int rsel = lane & 15, kq = lane >> 4;
    const int swz2 = ((rsel >> 1) & 3) << 4;
    const int abase = (wm * 128 + rsel) * 64 + ((kq * 16) ^ swz2);
    const int bbase = (wn * 64  + rsel) * 64 + ((kq * 16) ^ swz2);

    f32x4 acc[8][4] = {};

    // prologue: 7 region stages (tile0 complete + tile1 minus B-kh1)
    STAGE(pA, 0,     0, 0, 0);   // A-kh0(0)
    STAGE(pB, 32768, 0, 0, 0);   // B-kh0(0)
    STAGE(pA, 0,     1, 0, 0);   // A-kh1(0)
    STAGE(pB, 32768, 1, 0, 0);   // B-kh1(0)
    STAGE(pA, 0,     0, 1, 1);   // A-kh0(1)
    STAGE(pB, 32768, 0, 1, 1);   // B-kh0(1)
    STAGE(pA, 0,     1, 1, 1);   // A-kh1(1)

    // main loop: tiles 0..13 (7 dbuf pairs), all stages active
    for (int pp = 0; pp < 7; ++pp) {
        int t0 = 2 * pp;
        WAITVM(6); BARF(); TILE(t0,     0, 2);
        WAITVM(6); BARF(); TILE(t0 + 1, 1, 2);
    }
    // epilogue: t=14 stages only B-kh1(15); t=15 stages nothing
    WAITVM(6); BARF(); TILE(14, 0, 1);
    WAITVM(0); BARF(); TILE(15, 1, 0);

    // epilogue: C/D layout col=lane&15, row=(lane>>4)*4+reg  [m89/m91 verified]
    float* outb = out + ((size_t)b * LSEQ + l0) * NDIM + n0;
    const int rq = lane >> 4, cl = lane & 15;
    #pragma unroll
    for (int mi = 0; mi < 8; ++mi)
        #pragma unroll
        for (int ni = 0; ni < 4; ++ni) {
            int col = wn * 64 + ni * 16 + cl;
            #pragma unroll
            for (int r2 = 0; r2 < 4; ++r2) {
                int row = wm * 128 + mi * 16 + rq * 4 + r2;
                float v = acc[mi][ni][r2];
                outb[(size_t)row * NDIM + col] = 1.0f / (1.0f + __expf(-v));
            }
        }
}

#undef WAITVM
#undef LGKM0
#undef BARF
#undef STAGE
#undef RDA
#undef RDB
#undef MFMA16
#undef TILE

// ---------------------------------------------------------------------------
extern "C" void kernel_launch(void* const* d_in, const int* in_sizes, int n_in,
                              void* d_out, int out_size, void* d_ws, size_t ws_size,
                              hipStream_t stream) {
    (void)in_sizes; (void)n_in; (void)out_size; (void)ws_size;
    const float* X = (const float*)d_in[0];
    const float* W = (const float*)d_in[1];
    float* out = (float*)d_out;

    // workspace: s1|s2|rd (32K floats each) | P1|P2 (512K floats each)
    //            | Xb bf16 32MB | Bt bf16 64MB   (~100.4 MB, unchanged)
    float* s1 = (float*)d_ws;
    float* s2 = s1 + BATCH * NDIM;
    float* rd = s2 + BATCH * NDIM;
    float* P1 = rd + BATCH * NDIM;
    float* P2 = P1 + (size_t)NSPLIT * BATCH * NDIM;
    unsigned short* Xb = (unsigned short*)(P2 + (size_t)NSPLIT * BATCH * NDIM);
    unsigned short* Bt = Xb + (size_t)BATCH * LSEQ * NDIM;

    prep_kernel<<<dim3(NSPLIT, BATCH, 2), 256, 0, stream>>>(X, W, Xb, P1, P2);
    stats_kernel<<<256, 256, 0, stream>>>(P1, P2, s1, s2, rd);
    btgen_kernel<<<(BATCH * NDIM) / 4, 256, 0, stream>>>(s1, s2, rd, Bt);
    gemm_kernel<<<256, 512, 0, stream>>>(Xb, Bt, out);
}